// Round 1
// baseline (593.653 us; speedup 1.0000x reference)
//
#include <hip/hip_runtime.h>

typedef __attribute__((ext_vector_type(8))) short short8;
typedef __attribute__((ext_vector_type(4))) float f32x4;
typedef unsigned short u16;
typedef unsigned int u32;

#define DEVI __device__ __forceinline__

DEVI u16 f2b(float f) {
  u32 u = __float_as_uint(f);
  u32 r = u + 0x7FFFu + ((u >> 16) & 1u);   // RNE to bf16
  return (u16)(r >> 16);
}
DEVI float b2f(u16 h) { return __uint_as_float(((u32)h) << 16); }

constexpr int T_ = 8192, D_ = 1024, E_ = 16, F_ = 512, FS_ = 2048;

// ---------------- workspace layout (bytes) ----------------
constexpr size_t OFF_XB   = 0;                                  // x bf16 [T][D]
constexpr size_t OFF_WGT  = OFF_XB  + (size_t)T_ * D_ * 2;      // WgT bf16 [E][F][D]
constexpr size_t OFF_WUT  = OFF_WGT + (size_t)E_ * F_ * D_ * 2; // WuT bf16 [E][F][D]
constexpr size_t OFF_WDT  = OFF_WUT + (size_t)E_ * F_ * D_ * 2; // WdT bf16 [E][D][F]
constexpr size_t OFF_SGT  = OFF_WDT + (size_t)E_ * D_ * F_ * 2; // SgT bf16 [FS][D]
constexpr size_t OFF_SUT  = OFF_SGT + (size_t)FS_ * D_ * 2;     // SuT bf16 [FS][D]
constexpr size_t OFF_SDT  = OFF_SUT + (size_t)FS_ * D_ * 2;     // SdT bf16 [D][FS]
constexpr size_t OFF_HB   = OFF_SDT + (size_t)D_ * FS_ * 2;     // hbuf bf16 [2T][F] (by packed row)
constexpr size_t OFF_HS   = OFF_HB  + (size_t)2 * T_ * F_ * 2;  // hs bf16 [T][FS]
constexpr size_t OFF_PAIR = OFF_HS  + (size_t)T_ * FS_ * 2;     // pair bf16 [2T][D] (by slot)
constexpr size_t OFF_PW   = OFF_PAIR + (size_t)2 * T_ * D_ * 2; // pw f32 [2T]
constexpr size_t OFF_GATE = OFF_PW  + (size_t)2 * T_ * 4;       // gate f32 [T]
constexpr size_t OFF_CNT  = OFF_GATE + (size_t)T_ * 4;          // counts i32 [E]
constexpr size_t OFF_ROFF = OFF_CNT + 64;                       // row_off i32 [E]
constexpr size_t OFF_LIST = OFF_ROFF + 64;                      // lists i32 [E][T]

// ---------------- small kernels ----------------

__global__ void cvt_x_kernel(const float4* __restrict__ in, ushort4* __restrict__ out, int n4) {
  int i = blockIdx.x * blockDim.x + threadIdx.x;
  int stride = gridDim.x * blockDim.x;
  for (; i < n4; i += stride) {
    float4 v = in[i];
    out[i] = make_ushort4(f2b(v.x), f2b(v.y), f2b(v.z), f2b(v.w));
  }
}

// in fp32 [R][C] -> out bf16 [C][R]; batched over blockIdx.z
__global__ void transpose_cvt_kernel(const float* __restrict__ in, u16* __restrict__ out, int R, int C) {
  __shared__ float tile[32][33];
  size_t base = (size_t)blockIdx.z * R * C;
  in += base; out += base;
  int c0 = blockIdx.x * 32, r0 = blockIdx.y * 32;
  int tx = threadIdx.x, ty = threadIdx.y;
#pragma unroll
  for (int i = 0; i < 4; ++i)
    tile[ty + i * 8][tx] = in[(size_t)(r0 + ty + i * 8) * C + c0 + tx];
  __syncthreads();
#pragma unroll
  for (int i = 0; i < 4; ++i)
    out[(size_t)(c0 + ty + i * 8) * R + r0 + tx] = f2b(tile[tx][ty + i * 8]);
}

// one wave per token: 16 router logits + shared-gate dot, top-2, pair lists
__global__ void router_kernel(const float* __restrict__ x, const float* __restrict__ rw,
                              const float* __restrict__ sgw, int* __restrict__ counts,
                              int* __restrict__ lists, float* __restrict__ pw,
                              float* __restrict__ gate) {
  int t = blockIdx.x;
  int lane = threadIdx.x;
  const float* xr = x + (size_t)t * D_;
  float acc[17];
#pragma unroll
  for (int e = 0; e < 17; ++e) acc[e] = 0.f;
  for (int d = lane; d < D_; d += 64) {
    float xv = xr[d];
#pragma unroll
    for (int e = 0; e < 16; ++e) acc[e] = fmaf(xv, rw[e * D_ + d], acc[e]);
    acc[16] = fmaf(xv, sgw[d], acc[16]);
  }
#pragma unroll
  for (int e = 0; e < 17; ++e) {
    float v = acc[e];
#pragma unroll
    for (int off = 32; off; off >>= 1) v += __shfl_xor(v, off);
    acc[e] = v;
  }
  if (lane == 0) {
    int i1 = 0; float l1 = acc[0];
#pragma unroll
    for (int e = 1; e < 16; ++e) if (acc[e] > l1) { l1 = acc[e]; i1 = e; }
    int i2 = (i1 == 0) ? 1 : 0; float l2 = acc[i2];
#pragma unroll
    for (int e = 0; e < 16; ++e) {
      if (e == i1) continue;
      if (acc[e] > l2) { l2 = acc[e]; i2 = e; }
    }
    // top-2 renormalized softmax weights (full denominator cancels)
    float w1 = 1.f / (1.f + expf(l2 - l1));
    float w2 = 1.f - w1;
    int p1 = atomicAdd(&counts[i1], 1);
    lists[i1 * T_ + p1] = 2 * t;
    int p2 = atomicAdd(&counts[i2], 1);
    lists[i2 * T_ + p2] = 2 * t + 1;
    pw[2 * t] = w1;
    pw[2 * t + 1] = w2;
    gate[t] = 1.f / (1.f + expf(-acc[16]));
  }
}

__global__ void scan_kernel(const int* __restrict__ counts, int* __restrict__ row_off) {
  if (threadIdx.x == 0) {
    int s = 0;
    for (int e = 0; e < E_; ++e) { row_off[e] = s; s += counts[e]; }
  }
}

// ---------------- GEMM core ----------------
// All GEMMs: A [M][K] row-major bf16, B given transposed Bt [N][K] row-major bf16.
// Tile 128x128, BK=64, 4 waves, 64x64 per wave, mfma_f32_16x16x32_bf16.
// LDS rows are 128B; XOR swizzle byte ^= ((row&7)<<4) applied on the *global source*
// (global_load_lds writes linearly) and again on the ds_read side (rule #21).
//
// MODE 0: expert gate+up (dual B). A = x gathered by lists (token=slot>>1). out: hbuf bf16.
// MODE 1: expert down. A = hbuf (linear rows at row_off[e]). out: pair[slot] scaled by pw.
// MODE 2: shared gate+up (dual B). A = x linear. out: hs bf16.
// MODE 3: shared down + final. A = hs. out fp32 = gate*C + pair[2t] + pair[2t+1].
DEVI void gl_lds16(const void* gsrc, void* lds) {
  __builtin_amdgcn_global_load_lds((const __attribute__((address_space(1))) unsigned int*)gsrc,
                                   (__attribute__((address_space(3))) unsigned int*)lds, 16, 0, 0);
}

template <int MODE>
__global__ __launch_bounds__(256, 2) void moe_gemm(
    const u16* __restrict__ Abase, const u16* __restrict__ B0, const u16* __restrict__ B1,
    u16* __restrict__ outb, float* __restrict__ outf,
    const int* __restrict__ counts, const int* __restrict__ row_off,
    const int* __restrict__ lists, const float* __restrict__ pw,
    const float* __restrict__ gate, const u16* __restrict__ pairb, int Kdim) {
  constexpr bool DUAL = (MODE == 0 || MODE == 2);
  extern __shared__ char smem[];
  const int tid = threadIdx.x;
  const int mt = blockIdx.x, nt = blockIdx.y, e = blockIdx.z;

  int cnt = 0, roff = 0;
  const u16* A = Abase;
  if constexpr (MODE == 0 || MODE == 1) {
    cnt = counts[e];
    if (mt * 128 >= cnt) return;
    roff = row_off[e];
    if constexpr (MODE == 0) {
      B0 += (size_t)e * F_ * D_;
      B1 += (size_t)e * F_ * D_;
    } else {
      A = Abase + (size_t)roff * Kdim;
      B0 += (size_t)e * D_ * F_;
    }
  }

  const int lane = tid & 63, wid = tid >> 6;
  const int wm = wid >> 1, wn = wid & 1;
  const int lr = lane & 15, lg = lane >> 4;

  // staging source pointers (byte ptrs incl. swizzled k-slot, excl. ks*128)
  const int ldsrow = tid >> 3;          // 0..31
  const int kslot = (tid & 7) << 4;     // 0..112
  const size_t strideB = (size_t)Kdim * 2;
  const char* aSrc[4];
  const char* b0Src[4];
  const char* b1Src[4];
#pragma unroll
  for (int q = 0; q < 4; ++q) {
    int row = q * 32 + ldsrow;
    int kb = kslot ^ ((row & 7) << 4);
    long arow;
    if constexpr (MODE == 0) {
      int r = mt * 128 + row;
      arow = (r < cnt) ? (lists[e * T_ + r] >> 1) : 0;   // token index
    } else if constexpr (MODE == 1) {
      int r = mt * 128 + row;
      arow = (r < cnt) ? r : (cnt - 1);
    } else {
      arow = mt * 128 + row;
    }
    aSrc[q] = (const char*)A + (size_t)arow * strideB + kb;
    int nrow = nt * 128 + row;
    b0Src[q] = (const char*)B0 + (size_t)nrow * strideB + kb;
    if constexpr (DUAL) b1Src[q] = (const char*)B1 + (size_t)nrow * strideB + kb;
  }

  char* As = smem;
  char* Bs0 = smem + 16384;
  char* Bs1 = smem + 32768;

  const f32x4 fz = {0.f, 0.f, 0.f, 0.f};
  f32x4 acc0[4][4], acc1[4][4];
#pragma unroll
  for (int i = 0; i < 4; ++i)
#pragma unroll
    for (int j = 0; j < 4; ++j) { acc0[i][j] = fz; acc1[i][j] = fz; }

  const int nks = Kdim >> 6;
  const int sw = (lr & 7) << 4;
  for (int ks = 0; ks < nks; ++ks) {
    const int kbo = ks * 128;
#pragma unroll
    for (int q = 0; q < 4; ++q) gl_lds16(aSrc[q] + kbo, As + q * 4096 + tid * 16);
#pragma unroll
    for (int q = 0; q < 4; ++q) gl_lds16(b0Src[q] + kbo, Bs0 + q * 4096 + tid * 16);
    if constexpr (DUAL) {
#pragma unroll
      for (int q = 0; q < 4; ++q) gl_lds16(b1Src[q] + kbo, Bs1 + q * 4096 + tid * 16);
    }
    __syncthreads();
#pragma unroll
    for (int kk = 0; kk < 2; ++kk) {
      const int ko = kk * 64 + lg * 16;
      short8 af[4];
#pragma unroll
      for (int fm = 0; fm < 4; ++fm) {
        int row = wm * 64 + fm * 16 + lr;
        af[fm] = *(const short8*)(As + row * 128 + (ko ^ sw));
      }
#pragma unroll
      for (int fn = 0; fn < 4; ++fn) {
        int col = wn * 64 + fn * 16 + lr;
        int boff = col * 128 + (ko ^ sw);
        short8 bf0 = *(const short8*)(Bs0 + boff);
#pragma unroll
        for (int fm = 0; fm < 4; ++fm)
          acc0[fm][fn] = __builtin_amdgcn_mfma_f32_16x16x32_bf16(af[fm], bf0, acc0[fm][fn], 0, 0, 0);
        if constexpr (DUAL) {
          short8 bf1 = *(const short8*)(Bs1 + boff);
#pragma unroll
          for (int fm = 0; fm < 4; ++fm)
            acc1[fm][fn] = __builtin_amdgcn_mfma_f32_16x16x32_bf16(af[fm], bf1, acc1[fm][fn], 0, 0, 0);
        }
      }
    }
    __syncthreads();
  }

  // epilogue: C/D layout col = lane&15, row = (lane>>4)*4 + j  [verified]
  const int r0 = mt * 128;
#pragma unroll
  for (int fm = 0; fm < 4; ++fm) {
#pragma unroll
    for (int j = 0; j < 4; ++j) {
      const int rowt = wm * 64 + fm * 16 + lg * 4 + j;
      const int r = r0 + rowt;
      if constexpr (MODE == 0 || MODE == 1) {
        if (r >= cnt) continue;
      }
      int slot = 0;
      float rsc = 0.f;
      if constexpr (MODE == 1) { slot = lists[e * T_ + r]; rsc = pw[slot]; }
      if constexpr (MODE == 3) rsc = gate[r];
#pragma unroll
      for (int fn = 0; fn < 4; ++fn) {
        const int c = nt * 128 + wn * 64 + fn * 16 + lr;
        float v = acc0[fm][fn][j];
        if constexpr (MODE == 0) {
          float g = v, u = acc1[fm][fn][j];
          float h = g / (1.f + expf(-g)) * u;
          outb[(size_t)(roff + r) * F_ + c] = f2b(h);
        } else if constexpr (MODE == 1) {
          outb[(size_t)slot * D_ + c] = f2b(rsc * v);
        } else if constexpr (MODE == 2) {
          float g = v, u = acc1[fm][fn][j];
          float h = g / (1.f + expf(-g)) * u;
          outb[(size_t)r * FS_ + c] = f2b(h);
        } else {
          float o = v * rsc + b2f(pairb[(size_t)(2 * r) * D_ + c]) + b2f(pairb[(size_t)(2 * r + 1) * D_ + c]);
          outf[(size_t)r * D_ + c] = o;
        }
      }
    }
  }
}

// ---------------- launch ----------------
extern "C" void kernel_launch(void* const* d_in, const int* in_sizes, int n_in,
                              void* d_out, int out_size, void* d_ws, size_t ws_size,
                              hipStream_t stream) {
  const float* x   = (const float*)d_in[0];
  const float* rw  = (const float*)d_in[1];
  const float* Wg  = (const float*)d_in[2];
  const float* Wu  = (const float*)d_in[3];
  const float* Wd  = (const float*)d_in[4];
  const float* Sg  = (const float*)d_in[5];
  const float* Su  = (const float*)d_in[6];
  const float* Sd  = (const float*)d_in[7];
  const float* sgw = (const float*)d_in[8];
  float* out = (float*)d_out;

  unsigned char* ws = (unsigned char*)d_ws;
  u16* xb    = (u16*)(ws + OFF_XB);
  u16* wgT   = (u16*)(ws + OFF_WGT);
  u16* wuT   = (u16*)(ws + OFF_WUT);
  u16* wdT   = (u16*)(ws + OFF_WDT);
  u16* sgT   = (u16*)(ws + OFF_SGT);
  u16* suT   = (u16*)(ws + OFF_SUT);
  u16* sdT   = (u16*)(ws + OFF_SDT);
  u16* hb    = (u16*)(ws + OFF_HB);
  u16* hs    = (u16*)(ws + OFF_HS);
  u16* pairb = (u16*)(ws + OFF_PAIR);
  float* pwf   = (float*)(ws + OFF_PW);
  float* gatef = (float*)(ws + OFF_GATE);
  int* cnti    = (int*)(ws + OFF_CNT);
  int* roffi   = (int*)(ws + OFF_ROFF);
  int* listsi  = (int*)(ws + OFF_LIST);

  hipMemsetAsync(cnti, 0, 64, stream);

  cvt_x_kernel<<<2048, 256, 0, stream>>>((const float4*)x, (ushort4*)xb, T_ * D_ / 4);

  transpose_cvt_kernel<<<dim3(F_ / 32, D_ / 32, E_), dim3(32, 8), 0, stream>>>(Wg, wgT, D_, F_);
  transpose_cvt_kernel<<<dim3(F_ / 32, D_ / 32, E_), dim3(32, 8), 0, stream>>>(Wu, wuT, D_, F_);
  transpose_cvt_kernel<<<dim3(D_ / 32, F_ / 32, E_), dim3(32, 8), 0, stream>>>(Wd, wdT, F_, D_);
  transpose_cvt_kernel<<<dim3(FS_ / 32, D_ / 32, 1), dim3(32, 8), 0, stream>>>(Sg, sgT, D_, FS_);
  transpose_cvt_kernel<<<dim3(FS_ / 32, D_ / 32, 1), dim3(32, 8), 0, stream>>>(Su, suT, D_, FS_);
  transpose_cvt_kernel<<<dim3(D_ / 32, FS_ / 32, 1), dim3(32, 8), 0, stream>>>(Sd, sdT, FS_, D_);

  router_kernel<<<T_, 64, 0, stream>>>(x, rw, sgw, cnti, listsi, pwf, gatef);
  scan_kernel<<<1, 64, 0, stream>>>(cnti, roffi);

  // expert gate+up: K=1024, N=512
  moe_gemm<0><<<dim3(64, 4, 16), 256, 49152, stream>>>(xb, wgT, wuT, hb, nullptr,
                                                       cnti, roffi, listsi, pwf, gatef, nullptr, 1024);
  // expert down: K=512, N=1024
  moe_gemm<1><<<dim3(64, 8, 16), 256, 32768, stream>>>(hb, wdT, nullptr, pairb, nullptr,
                                                       cnti, roffi, listsi, pwf, gatef, nullptr, 512);
  // shared gate+up: K=1024, N=2048
  moe_gemm<2><<<dim3(64, 16, 1), 256, 49152, stream>>>(xb, sgT, suT, hs, nullptr,
                                                       cnti, roffi, listsi, pwf, gatef, nullptr, 1024);
  // shared down + final combine: K=2048, N=1024
  moe_gemm<3><<<dim3(64, 8, 1), 256, 32768, stream>>>(hs, sdT, nullptr, nullptr, out,
                                                      cnti, roffi, listsi, pwf, gatef, pairb, 2048);

  (void)in_sizes; (void)n_in; (void)out_size; (void)ws_size;
}

// Round 2
// 582.579 us; speedup vs baseline: 1.0190x; 1.0190x over previous
//
#include <hip/hip_runtime.h>

typedef __attribute__((ext_vector_type(8))) short short8;
typedef __attribute__((ext_vector_type(4))) float f32x4;
typedef unsigned short u16;
typedef unsigned int u32;

#define DEVI __device__ __forceinline__

DEVI u16 f2b(float f) {
  u32 u = __float_as_uint(f);
  u32 r = u + 0x7FFFu + ((u >> 16) & 1u);   // RNE to bf16
  return (u16)(r >> 16);
}
DEVI float b2f(u16 h) { return __uint_as_float(((u32)h) << 16); }

constexpr int T_ = 8192, D_ = 1024, E_ = 16, F_ = 512, FS_ = 2048;

// ---------------- workspace layout (bytes) ----------------
constexpr size_t OFF_XB   = 0;                                  // x bf16 [T][D]
constexpr size_t OFF_WGT  = OFF_XB  + (size_t)T_ * D_ * 2;      // WgT bf16 [E][F][D]
constexpr size_t OFF_WUT  = OFF_WGT + (size_t)E_ * F_ * D_ * 2; // WuT bf16 [E][F][D]
constexpr size_t OFF_WDT  = OFF_WUT + (size_t)E_ * F_ * D_ * 2; // WdT bf16 [E][D][F]
constexpr size_t OFF_SGT  = OFF_WDT + (size_t)E_ * D_ * F_ * 2; // SgT bf16 [FS][D]
constexpr size_t OFF_SUT  = OFF_SGT + (size_t)FS_ * D_ * 2;     // SuT bf16 [FS][D]
constexpr size_t OFF_SDT  = OFF_SUT + (size_t)FS_ * D_ * 2;     // SdT bf16 [D][FS]
constexpr size_t OFF_HB   = OFF_SDT + (size_t)D_ * FS_ * 2;     // hbuf bf16 [2T][F] (by packed row)
constexpr size_t OFF_HS   = OFF_HB  + (size_t)2 * T_ * F_ * 2;  // hs bf16 [T][FS]
constexpr size_t OFF_PAIR = OFF_HS  + (size_t)T_ * FS_ * 2;     // pair bf16 [2T][D] (by slot)
constexpr size_t OFF_PW   = OFF_PAIR + (size_t)2 * T_ * D_ * 2; // pw f32 [2T]
constexpr size_t OFF_GATE = OFF_PW  + (size_t)2 * T_ * 4;       // gate f32 [T]
constexpr size_t OFF_CNT  = OFF_GATE + (size_t)T_ * 4;          // counts i32 [E]
constexpr size_t OFF_ROFF = OFF_CNT + 64;                       // row_off i32 [E]
constexpr size_t OFF_LIST = OFF_ROFF + 64;                      // lists i32 [E][T]

// ---------------- small kernels ----------------

// in fp32 [R][C] -> out bf16 [C][R]; batched over blockIdx.z
__global__ void transpose_cvt_kernel(const float* __restrict__ in, u16* __restrict__ out, int R, int C) {
  __shared__ float tile[32][33];
  size_t base = (size_t)blockIdx.z * R * C;
  in += base; out += base;
  int c0 = blockIdx.x * 32, r0 = blockIdx.y * 32;
  int tx = threadIdx.x, ty = threadIdx.y;
#pragma unroll
  for (int i = 0; i < 4; ++i)
    tile[ty + i * 8][tx] = in[(size_t)(r0 + ty + i * 8) * C + c0 + tx];
  __syncthreads();
#pragma unroll
  for (int i = 0; i < 4; ++i)
    out[(size_t)(c0 + ty + i * 8) * R + r0 + tx] = f2b(tile[tx][ty + i * 8]);
}

// router v2: 4 waves/block, one token per wave per grid-stride step.
// float4 loads for x; 16+1 float4 weight streams (L1-resident, 68KB);
// fused x -> bf16 conversion (replaces separate cvt_x pass).
__global__ __launch_bounds__(256) void router_kernel(
    const float4* __restrict__ x4, const float4* __restrict__ rw4,
    const float4* __restrict__ sgw4, int* __restrict__ counts,
    int* __restrict__ lists, float* __restrict__ pw,
    float* __restrict__ gate, ushort4* __restrict__ xb4) {
  const int lane = threadIdx.x & 63, wid = threadIdx.x >> 6;
  const int w0 = blockIdx.x * 4 + wid, wstride = gridDim.x * 4;
  for (int t = w0; t < T_; t += wstride) {
    const float4* xr = x4 + (size_t)t * (D_ / 4);
    float acc[17];
#pragma unroll
    for (int e = 0; e < 17; ++e) acc[e] = 0.f;
    ushort4 xo[4];
#pragma unroll
    for (int j = 0; j < 4; ++j) {
      const int d4 = j * 64 + lane;
      float4 xv = xr[d4];
      xo[j] = make_ushort4(f2b(xv.x), f2b(xv.y), f2b(xv.z), f2b(xv.w));
#pragma unroll
      for (int e = 0; e < 16; ++e) {
        float4 wv = rw4[e * 256 + d4];
        acc[e] = fmaf(xv.x, wv.x, fmaf(xv.y, wv.y, fmaf(xv.z, wv.z, fmaf(xv.w, wv.w, acc[e]))));
      }
      float4 sv = sgw4[d4];
      acc[16] = fmaf(xv.x, sv.x, fmaf(xv.y, sv.y, fmaf(xv.z, sv.z, fmaf(xv.w, sv.w, acc[16]))));
    }
#pragma unroll
    for (int j = 0; j < 4; ++j)
      xb4[(size_t)t * 256 + j * 64 + lane] = xo[j];
#pragma unroll
    for (int e = 0; e < 17; ++e) {
      float v = acc[e];
#pragma unroll
      for (int off = 32; off; off >>= 1) v += __shfl_xor(v, off);
      acc[e] = v;
    }
    if (lane == 0) {
      int i1 = 0; float l1 = acc[0];
#pragma unroll
      for (int e = 1; e < 16; ++e) if (acc[e] > l1) { l1 = acc[e]; i1 = e; }
      int i2 = (i1 == 0) ? 1 : 0; float l2 = acc[i2];
#pragma unroll
      for (int e = 0; e < 16; ++e) {
        if (e == i1) continue;
        if (acc[e] > l2) { l2 = acc[e]; i2 = e; }
      }
      float w1 = 1.f / (1.f + expf(l2 - l1));
      float w2 = 1.f - w1;
      int p1 = atomicAdd(&counts[i1], 1);
      lists[i1 * T_ + p1] = 2 * t;
      int p2 = atomicAdd(&counts[i2], 1);
      lists[i2 * T_ + p2] = 2 * t + 1;
      pw[2 * t] = w1;
      pw[2 * t + 1] = w2;
      gate[t] = 1.f / (1.f + expf(-acc[16]));
    }
  }
}

__global__ void scan_kernel(const int* __restrict__ counts, int* __restrict__ row_off) {
  if (threadIdx.x == 0) {
    int s = 0;
    for (int e = 0; e < E_; ++e) { row_off[e] = s; s += counts[e]; }
  }
}

// ---------------- GEMM core ----------------
// All GEMMs: A [M][K] row-major bf16, B given transposed Bt [N][K] row-major bf16.
// Tile 128x128, BK=64, 4 waves, 64x64 per wave, mfma_f32_16x16x32_bf16.
// LDS rows are 128B; XOR swizzle byte ^= ((row&7)<<4) applied on the *global source*
// (global_load_lds writes linearly) and again on the ds_read side (rule #21).
//
// MODE 0: expert gate+up (dual B). A = x gathered by lists (token=slot>>1). out: hbuf bf16.
// MODE 1: expert down. A = hbuf (linear rows at row_off[e]). out: pair[slot] scaled by pw.
// MODE 2: shared gate+up (dual B). A = x linear. out: hs bf16.
// MODE 3: shared down + final. A = hs. out fp32 = gate*C + pair[2t] + pair[2t+1].
DEVI void gl_lds16(const void* gsrc, void* lds) {
  __builtin_amdgcn_global_load_lds((const __attribute__((address_space(1))) unsigned int*)gsrc,
                                   (__attribute__((address_space(3))) unsigned int*)lds, 16, 0, 0);
}

template <int MODE>
__global__ __launch_bounds__(256, 2) void moe_gemm(
    const u16* __restrict__ Abase, const u16* __restrict__ B0, const u16* __restrict__ B1,
    u16* __restrict__ outb, float* __restrict__ outf,
    const int* __restrict__ counts, const int* __restrict__ row_off,
    const int* __restrict__ lists, const float* __restrict__ pw,
    const float* __restrict__ gate, const u16* __restrict__ pairb, int Kdim) {
  constexpr bool DUAL = (MODE == 0 || MODE == 2);
  extern __shared__ char smem[];
  const int tid = threadIdx.x;
  const int mt = blockIdx.x, nt = blockIdx.y, e = blockIdx.z;

  int cnt = 0, roff = 0;
  const u16* A = Abase;
  if constexpr (MODE == 0 || MODE == 1) {
    cnt = counts[e];
    if (mt * 128 >= cnt) return;
    roff = row_off[e];
    if constexpr (MODE == 0) {
      B0 += (size_t)e * F_ * D_;
      B1 += (size_t)e * F_ * D_;
    } else {
      A = Abase + (size_t)roff * Kdim;
      B0 += (size_t)e * D_ * F_;
    }
  }

  const int lane = tid & 63, wid = tid >> 6;
  const int wm = wid >> 1, wn = wid & 1;
  const int lr = lane & 15, lg = lane >> 4;

  // staging source pointers (byte ptrs incl. swizzled k-slot, excl. ks*128)
  const int ldsrow = tid >> 3;          // 0..31
  const int kslot = (tid & 7) << 4;     // 0..112
  const size_t strideB = (size_t)Kdim * 2;
  const char* aSrc[4];
  const char* b0Src[4];
  const char* b1Src[4];
#pragma unroll
  for (int q = 0; q < 4; ++q) {
    int row = q * 32 + ldsrow;
    int kb = kslot ^ ((row & 7) << 4);
    long arow;
    if constexpr (MODE == 0) {
      int r = mt * 128 + row;
      arow = (r < cnt) ? (lists[e * T_ + r] >> 1) : 0;   // token index
    } else if constexpr (MODE == 1) {
      int r = mt * 128 + row;
      arow = (r < cnt) ? r : (cnt - 1);
    } else {
      arow = mt * 128 + row;
    }
    aSrc[q] = (const char*)A + (size_t)arow * strideB + kb;
    int nrow = nt * 128 + row;
    b0Src[q] = (const char*)B0 + (size_t)nrow * strideB + kb;
    if constexpr (DUAL) b1Src[q] = (const char*)B1 + (size_t)nrow * strideB + kb;
  }

  char* As = smem;
  char* Bs0 = smem + 16384;
  char* Bs1 = smem + 32768;

  const f32x4 fz = {0.f, 0.f, 0.f, 0.f};
  f32x4 acc0[4][4], acc1[4][4];
#pragma unroll
  for (int i = 0; i < 4; ++i)
#pragma unroll
    for (int j = 0; j < 4; ++j) { acc0[i][j] = fz; acc1[i][j] = fz; }

  const int nks = Kdim >> 6;
  const int sw = (lr & 7) << 4;
  for (int ks = 0; ks < nks; ++ks) {
    const int kbo = ks * 128;
#pragma unroll
    for (int q = 0; q < 4; ++q) gl_lds16(aSrc[q] + kbo, As + q * 4096 + tid * 16);
#pragma unroll
    for (int q = 0; q < 4; ++q) gl_lds16(b0Src[q] + kbo, Bs0 + q * 4096 + tid * 16);
    if constexpr (DUAL) {
#pragma unroll
      for (int q = 0; q < 4; ++q) gl_lds16(b1Src[q] + kbo, Bs1 + q * 4096 + tid * 16);
    }
    __syncthreads();
#pragma unroll
    for (int kk = 0; kk < 2; ++kk) {
      const int ko = kk * 64 + lg * 16;
      short8 af[4];
#pragma unroll
      for (int fm = 0; fm < 4; ++fm) {
        int row = wm * 64 + fm * 16 + lr;
        af[fm] = *(const short8*)(As + row * 128 + (ko ^ sw));
      }
#pragma unroll
      for (int fn = 0; fn < 4; ++fn) {
        int col = wn * 64 + fn * 16 + lr;
        int boff = col * 128 + (ko ^ sw);
        short8 bf0 = *(const short8*)(Bs0 + boff);
#pragma unroll
        for (int fm = 0; fm < 4; ++fm)
          acc0[fm][fn] = __builtin_amdgcn_mfma_f32_16x16x32_bf16(af[fm], bf0, acc0[fm][fn], 0, 0, 0);
        if constexpr (DUAL) {
          short8 bf1 = *(const short8*)(Bs1 + boff);
#pragma unroll
          for (int fm = 0; fm < 4; ++fm)
            acc1[fm][fn] = __builtin_amdgcn_mfma_f32_16x16x32_bf16(af[fm], bf1, acc1[fm][fn], 0, 0, 0);
        }
      }
    }
    __syncthreads();
  }

  // epilogue: C/D layout col = lane&15, row = (lane>>4)*4 + j  [verified]
  const int r0 = mt * 128;
#pragma unroll
  for (int fm = 0; fm < 4; ++fm) {
#pragma unroll
    for (int j = 0; j < 4; ++j) {
      const int rowt = wm * 64 + fm * 16 + lg * 4 + j;
      const int r = r0 + rowt;
      if constexpr (MODE == 0 || MODE == 1) {
        if (r >= cnt) continue;
      }
      int slot = 0;
      float rsc = 0.f;
      if constexpr (MODE == 1) { slot = lists[e * T_ + r]; rsc = pw[slot]; }
      if constexpr (MODE == 3) rsc = gate[r];
#pragma unroll
      for (int fn = 0; fn < 4; ++fn) {
        const int c = nt * 128 + wn * 64 + fn * 16 + lr;
        float v = acc0[fm][fn][j];
        if constexpr (MODE == 0) {
          float g = v, u = acc1[fm][fn][j];
          float h = g / (1.f + expf(-g)) * u;
          outb[(size_t)(roff + r) * F_ + c] = f2b(h);
        } else if constexpr (MODE == 1) {
          outb[(size_t)slot * D_ + c] = f2b(rsc * v);
        } else if constexpr (MODE == 2) {
          float g = v, u = acc1[fm][fn][j];
          float h = g / (1.f + expf(-g)) * u;
          outb[(size_t)r * FS_ + c] = f2b(h);
        } else {
          float o = v * rsc + b2f(pairb[(size_t)(2 * r) * D_ + c]) + b2f(pairb[(size_t)(2 * r + 1) * D_ + c]);
          outf[(size_t)r * D_ + c] = o;
        }
      }
    }
  }
}

// ---------------- launch ----------------
extern "C" void kernel_launch(void* const* d_in, const int* in_sizes, int n_in,
                              void* d_out, int out_size, void* d_ws, size_t ws_size,
                              hipStream_t stream) {
  const float* x   = (const float*)d_in[0];
  const float* rw  = (const float*)d_in[1];
  const float* Wg  = (const float*)d_in[2];
  const float* Wu  = (const float*)d_in[3];
  const float* Wd  = (const float*)d_in[4];
  const float* Sg  = (const float*)d_in[5];
  const float* Su  = (const float*)d_in[6];
  const float* Sd  = (const float*)d_in[7];
  const float* sgw = (const float*)d_in[8];
  float* out = (float*)d_out;

  unsigned char* ws = (unsigned char*)d_ws;
  u16* xb    = (u16*)(ws + OFF_XB);
  u16* wgT   = (u16*)(ws + OFF_WGT);
  u16* wuT   = (u16*)(ws + OFF_WUT);
  u16* wdT   = (u16*)(ws + OFF_WDT);
  u16* sgT   = (u16*)(ws + OFF_SGT);
  u16* suT   = (u16*)(ws + OFF_SUT);
  u16* sdT   = (u16*)(ws + OFF_SDT);
  u16* hb    = (u16*)(ws + OFF_HB);
  u16* hs    = (u16*)(ws + OFF_HS);
  u16* pairb = (u16*)(ws + OFF_PAIR);
  float* pwf   = (float*)(ws + OFF_PW);
  float* gatef = (float*)(ws + OFF_GATE);
  int* cnti    = (int*)(ws + OFF_CNT);
  int* roffi   = (int*)(ws + OFF_ROFF);
  int* listsi  = (int*)(ws + OFF_LIST);

  hipMemsetAsync(cnti, 0, 64, stream);

  transpose_cvt_kernel<<<dim3(F_ / 32, D_ / 32, E_), dim3(32, 8), 0, stream>>>(Wg, wgT, D_, F_);
  transpose_cvt_kernel<<<dim3(F_ / 32, D_ / 32, E_), dim3(32, 8), 0, stream>>>(Wu, wuT, D_, F_);
  transpose_cvt_kernel<<<dim3(D_ / 32, F_ / 32, E_), dim3(32, 8), 0, stream>>>(Wd, wdT, F_, D_);
  transpose_cvt_kernel<<<dim3(FS_ / 32, D_ / 32, 1), dim3(32, 8), 0, stream>>>(Sg, sgT, D_, FS_);
  transpose_cvt_kernel<<<dim3(FS_ / 32, D_ / 32, 1), dim3(32, 8), 0, stream>>>(Su, suT, D_, FS_);
  transpose_cvt_kernel<<<dim3(D_ / 32, FS_ / 32, 1), dim3(32, 8), 0, stream>>>(Sd, sdT, FS_, D_);

  router_kernel<<<1024, 256, 0, stream>>>((const float4*)x, (const float4*)rw,
                                          (const float4*)sgw, cnti, listsi, pwf, gatef,
                                          (ushort4*)xb);
  scan_kernel<<<1, 64, 0, stream>>>(cnti, roffi);

  // expert gate+up: K=1024, N=512
  moe_gemm<0><<<dim3(64, 4, 16), 256, 49152, stream>>>(xb, wgT, wuT, hb, nullptr,
                                                       cnti, roffi, listsi, pwf, gatef, nullptr, 1024);
  // expert down: K=512, N=1024
  moe_gemm<1><<<dim3(64, 8, 16), 256, 32768, stream>>>(hb, wdT, nullptr, pairb, nullptr,
                                                       cnti, roffi, listsi, pwf, gatef, nullptr, 512);
  // shared gate+up: K=1024, N=2048
  moe_gemm<2><<<dim3(64, 16, 1), 256, 49152, stream>>>(xb, sgT, suT, hs, nullptr,
                                                       cnti, roffi, listsi, pwf, gatef, nullptr, 1024);
  // shared down + final combine: K=2048, N=1024
  moe_gemm<3><<<dim3(64, 8, 1), 256, 32768, stream>>>(hs, sdT, nullptr, nullptr, out,
                                                      cnti, roffi, listsi, pwf, gatef, pairb, 2048);

  (void)in_sizes; (void)n_in; (void)out_size; (void)ws_size;
}

// Round 3
// 444.025 us; speedup vs baseline: 1.3370x; 1.3120x over previous
//
#include <hip/hip_runtime.h>

typedef __attribute__((ext_vector_type(8))) short short8;
typedef __attribute__((ext_vector_type(4))) float f32x4;
typedef unsigned short u16;
typedef unsigned int u32;

#define DEVI __device__ __forceinline__

DEVI u16 f2b(float f) {
  u32 u = __float_as_uint(f);
  u32 r = u + 0x7FFFu + ((u >> 16) & 1u);   // RNE to bf16
  return (u16)(r >> 16);
}
DEVI float b2f(u16 h) { return __uint_as_float(((u32)h) << 16); }

constexpr int T_ = 8192, D_ = 1024, E_ = 16, F_ = 512, FS_ = 2048;

// ---------------- workspace layout (bytes) ----------------
constexpr size_t OFF_XB   = 0;                                  // x bf16 [T][D]
constexpr size_t OFF_WGT  = OFF_XB  + (size_t)T_ * D_ * 2;      // WgT bf16 [E][F][D]
constexpr size_t OFF_WUT  = OFF_WGT + (size_t)E_ * F_ * D_ * 2; // WuT bf16 [E][F][D]
constexpr size_t OFF_WDT  = OFF_WUT + (size_t)E_ * F_ * D_ * 2; // WdT bf16 [E][D][F]
constexpr size_t OFF_SGT  = OFF_WDT + (size_t)E_ * D_ * F_ * 2; // SgT bf16 [FS][D]
constexpr size_t OFF_SUT  = OFF_SGT + (size_t)FS_ * D_ * 2;     // SuT bf16 [FS][D]
constexpr size_t OFF_SDT  = OFF_SUT + (size_t)FS_ * D_ * 2;     // SdT bf16 [D][FS]
constexpr size_t OFF_HB   = OFF_SDT + (size_t)D_ * FS_ * 2;     // hbuf bf16 [2T][F] (by packed row)
constexpr size_t OFF_HS   = OFF_HB  + (size_t)2 * T_ * F_ * 2;  // hs bf16 [T][FS]
constexpr size_t OFF_PAIR = OFF_HS  + (size_t)T_ * FS_ * 2;     // pair bf16 [2T][D] (by slot)
constexpr size_t OFF_PW   = OFF_PAIR + (size_t)2 * T_ * D_ * 2; // pw f32 [2T]
constexpr size_t OFF_GATE = OFF_PW  + (size_t)2 * T_ * 4;       // gate f32 [T]
constexpr size_t OFF_CNT  = OFF_GATE + (size_t)T_ * 4;          // counts i32 [E]
constexpr size_t OFF_ROFF = OFF_CNT + 64;                       // row_off i32 [E]
constexpr size_t OFF_TOP2 = OFF_ROFF + 64;                      // top2e packed i32 [T]
constexpr size_t OFF_LIST = OFF_TOP2 + (size_t)T_ * 4;          // lists i32 [E][T]

// ---------------- small kernels ----------------

// in fp32 [R][C] -> out bf16 [C][R]; batched over blockIdx.z
__global__ void transpose_cvt_kernel(const float* __restrict__ in, u16* __restrict__ out, int R, int C) {
  __shared__ float tile[32][33];
  size_t base = (size_t)blockIdx.z * R * C;
  in += base; out += base;
  int c0 = blockIdx.x * 32, r0 = blockIdx.y * 32;
  int tx = threadIdx.x, ty = threadIdx.y;
#pragma unroll
  for (int i = 0; i < 4; ++i)
    tile[ty + i * 8][tx] = in[(size_t)(r0 + ty + i * 8) * C + c0 + tx];
  __syncthreads();
#pragma unroll
  for (int i = 0; i < 4; ++i)
    out[(size_t)(c0 + ty + i * 8) * R + r0 + tx] = f2b(tile[tx][ty + i * 8]);
}

// router phase A: 4 waves/block, one token per wave per grid-stride step.
// NO atomics: lane0 writes packed top-2 experts, pair weights, gate.
// Fused x -> bf16 conversion.
__global__ __launch_bounds__(256) void router_kernel(
    const float4* __restrict__ x4, const float4* __restrict__ rw4,
    const float4* __restrict__ sgw4, int* __restrict__ top2e,
    float* __restrict__ pw, float* __restrict__ gate, ushort4* __restrict__ xb4) {
  const int lane = threadIdx.x & 63, wid = threadIdx.x >> 6;
  const int w0 = blockIdx.x * 4 + wid, wstride = gridDim.x * 4;
  for (int t = w0; t < T_; t += wstride) {
    const float4* xr = x4 + (size_t)t * (D_ / 4);
    float acc[17];
#pragma unroll
    for (int e = 0; e < 17; ++e) acc[e] = 0.f;
    ushort4 xo[4];
#pragma unroll
    for (int j = 0; j < 4; ++j) {
      const int d4 = j * 64 + lane;
      float4 xv = xr[d4];
      xo[j] = make_ushort4(f2b(xv.x), f2b(xv.y), f2b(xv.z), f2b(xv.w));
#pragma unroll
      for (int e = 0; e < 16; ++e) {
        float4 wv = rw4[e * 256 + d4];
        acc[e] = fmaf(xv.x, wv.x, fmaf(xv.y, wv.y, fmaf(xv.z, wv.z, fmaf(xv.w, wv.w, acc[e]))));
      }
      float4 sv = sgw4[d4];
      acc[16] = fmaf(xv.x, sv.x, fmaf(xv.y, sv.y, fmaf(xv.z, sv.z, fmaf(xv.w, sv.w, acc[16]))));
    }
#pragma unroll
    for (int j = 0; j < 4; ++j)
      xb4[(size_t)t * 256 + j * 64 + lane] = xo[j];
#pragma unroll
    for (int e = 0; e < 17; ++e) {
      float v = acc[e];
#pragma unroll
      for (int off = 32; off; off >>= 1) v += __shfl_xor(v, off);
      acc[e] = v;
    }
    if (lane == 0) {
      int i1 = 0; float l1 = acc[0];
#pragma unroll
      for (int e = 1; e < 16; ++e) if (acc[e] > l1) { l1 = acc[e]; i1 = e; }
      int i2 = (i1 == 0) ? 1 : 0; float l2 = acc[i2];
#pragma unroll
      for (int e = 0; e < 16; ++e) {
        if (e == i1) continue;
        if (acc[e] > l2) { l2 = acc[e]; i2 = e; }
      }
      float w1 = 1.f / (1.f + expf(l2 - l1));
      float w2 = 1.f - w1;
      top2e[t] = i1 | (i2 << 8);
      pw[2 * t] = w1;
      pw[2 * t + 1] = w2;
      gate[t] = 1.f / (1.f + expf(-acc[16]));
    }
  }
}

// router phase B: one block per expert; token-ordered compaction via
// ballot/popcount prefix sums. Deterministic, atomic-free.
__global__ __launch_bounds__(256) void compact_kernel(
    const int* __restrict__ top2e, int* __restrict__ lists, int* __restrict__ counts) {
  const int e = blockIdx.x;
  const int tid = threadIdx.x, lane = tid & 63, wid = tid >> 6;
  __shared__ int wsum[4];
  __shared__ int base;
  if (tid == 0) base = 0;
  __syncthreads();
  for (int c0 = 0; c0 < T_; c0 += 256) {
    const int t = c0 + tid;
    const int pk = top2e[t];
    int slot = -1;
    if ((pk & 0xFF) == e) slot = 2 * t;
    else if (((pk >> 8) & 0xFF) == e) slot = 2 * t + 1;
    const unsigned long long m = __ballot(slot >= 0);
    const int myofs = __popcll(m & ((1ULL << lane) - 1ULL));
    if (lane == 0) wsum[wid] = __popcll(m);
    __syncthreads();
    const int b = base;
    int wbase = 0;
#pragma unroll
    for (int w = 0; w < 4; ++w) if (w < wid) wbase += wsum[w];
    if (slot >= 0) lists[e * T_ + b + wbase + myofs] = slot;
    __syncthreads();
    if (tid == 0) base += wsum[0] + wsum[1] + wsum[2] + wsum[3];
    __syncthreads();
  }
  if (tid == 0) counts[e] = base;
}

__global__ void scan_kernel(const int* __restrict__ counts, int* __restrict__ row_off) {
  if (threadIdx.x == 0) {
    int s = 0;
    for (int e = 0; e < E_; ++e) { row_off[e] = s; s += counts[e]; }
  }
}

// ---------------- GEMM core ----------------
// All GEMMs: A [M][K] row-major bf16, B given transposed Bt [N][K] row-major bf16.
// Tile 128x128, BK=64, 4 waves, 64x64 per wave, mfma_f32_16x16x32_bf16.
// LDS rows are 128B; XOR swizzle byte ^= ((row&7)<<4) applied on the *global source*
// (global_load_lds writes linearly) and again on the ds_read side (rule #21).
//
// MODE 0: expert gate+up (dual B). A = x gathered by lists (token=slot>>1). out: hbuf bf16.
// MODE 1: expert down. A = hbuf (linear rows at row_off[e]). out: pair[slot] scaled by pw.
// MODE 2: shared gate+up (dual B). A = x linear. out: hs bf16.
// MODE 3: shared down + final. A = hs. out fp32 = gate*C + pair[2t] + pair[2t+1].
DEVI void gl_lds16(const void* gsrc, void* lds) {
  __builtin_amdgcn_global_load_lds((const __attribute__((address_space(1))) unsigned int*)gsrc,
                                   (__attribute__((address_space(3))) unsigned int*)lds, 16, 0, 0);
}

template <int MODE>
__global__ __launch_bounds__(256, 2) void moe_gemm(
    const u16* __restrict__ Abase, const u16* __restrict__ B0, const u16* __restrict__ B1,
    u16* __restrict__ outb, float* __restrict__ outf,
    const int* __restrict__ counts, const int* __restrict__ row_off,
    const int* __restrict__ lists, const float* __restrict__ pw,
    const float* __restrict__ gate, const u16* __restrict__ pairb, int Kdim) {
  constexpr bool DUAL = (MODE == 0 || MODE == 2);
  extern __shared__ char smem[];
  const int tid = threadIdx.x;
  const int mt = blockIdx.x, nt = blockIdx.y, e = blockIdx.z;

  int cnt = 0, roff = 0;
  const u16* A = Abase;
  if constexpr (MODE == 0 || MODE == 1) {
    cnt = counts[e];
    if (mt * 128 >= cnt) return;
    roff = row_off[e];
    if constexpr (MODE == 0) {
      B0 += (size_t)e * F_ * D_;
      B1 += (size_t)e * F_ * D_;
    } else {
      A = Abase + (size_t)roff * Kdim;
      B0 += (size_t)e * D_ * F_;
    }
  }

  const int lane = tid & 63, wid = tid >> 6;
  const int wm = wid >> 1, wn = wid & 1;
  const int lr = lane & 15, lg = lane >> 4;

  // staging source pointers (byte ptrs incl. swizzled k-slot, excl. ks*128)
  const int ldsrow = tid >> 3;          // 0..31
  const int kslot = (tid & 7) << 4;     // 0..112
  const size_t strideB = (size_t)Kdim * 2;
  const char* aSrc[4];
  const char* b0Src[4];
  const char* b1Src[4];
#pragma unroll
  for (int q = 0; q < 4; ++q) {
    int row = q * 32 + ldsrow;
    int kb = kslot ^ ((row & 7) << 4);
    long arow;
    if constexpr (MODE == 0) {
      int r = mt * 128 + row;
      arow = (r < cnt) ? (lists[e * T_ + r] >> 1) : 0;   // token index
    } else if constexpr (MODE == 1) {
      int r = mt * 128 + row;
      arow = (r < cnt) ? r : (cnt - 1);
    } else {
      arow = mt * 128 + row;
    }
    aSrc[q] = (const char*)A + (size_t)arow * strideB + kb;
    int nrow = nt * 128 + row;
    b0Src[q] = (const char*)B0 + (size_t)nrow * strideB + kb;
    if constexpr (DUAL) b1Src[q] = (const char*)B1 + (size_t)nrow * strideB + kb;
  }

  char* As = smem;
  char* Bs0 = smem + 16384;
  char* Bs1 = smem + 32768;

  const f32x4 fz = {0.f, 0.f, 0.f, 0.f};
  f32x4 acc0[4][4], acc1[4][4];
#pragma unroll
  for (int i = 0; i < 4; ++i)
#pragma unroll
    for (int j = 0; j < 4; ++j) { acc0[i][j] = fz; acc1[i][j] = fz; }

  const int nks = Kdim >> 6;
  const int sw = (lr & 7) << 4;
  for (int ks = 0; ks < nks; ++ks) {
    const int kbo = ks * 128;
#pragma unroll
    for (int q = 0; q < 4; ++q) gl_lds16(aSrc[q] + kbo, As + q * 4096 + tid * 16);
#pragma unroll
    for (int q = 0; q < 4; ++q) gl_lds16(b0Src[q] + kbo, Bs0 + q * 4096 + tid * 16);
    if constexpr (DUAL) {
#pragma unroll
      for (int q = 0; q < 4; ++q) gl_lds16(b1Src[q] + kbo, Bs1 + q * 4096 + tid * 16);
    }
    __syncthreads();
#pragma unroll
    for (int kk = 0; kk < 2; ++kk) {
      const int ko = kk * 64 + lg * 16;
      short8 af[4];
#pragma unroll
      for (int fm = 0; fm < 4; ++fm) {
        int row = wm * 64 + fm * 16 + lr;
        af[fm] = *(const short8*)(As + row * 128 + (ko ^ sw));
      }
#pragma unroll
      for (int fn = 0; fn < 4; ++fn) {
        int col = wn * 64 + fn * 16 + lr;
        int boff = col * 128 + (ko ^ sw);
        short8 bf0 = *(const short8*)(Bs0 + boff);
#pragma unroll
        for (int fm = 0; fm < 4; ++fm)
          acc0[fm][fn] = __builtin_amdgcn_mfma_f32_16x16x32_bf16(af[fm], bf0, acc0[fm][fn], 0, 0, 0);
        if constexpr (DUAL) {
          short8 bf1 = *(const short8*)(Bs1 + boff);
#pragma unroll
          for (int fm = 0; fm < 4; ++fm)
            acc1[fm][fn] = __builtin_amdgcn_mfma_f32_16x16x32_bf16(af[fm], bf1, acc1[fm][fn], 0, 0, 0);
        }
      }
    }
    __syncthreads();
  }

  // epilogue: C/D layout col = lane&15, row = (lane>>4)*4 + j  [verified]
  const int r0 = mt * 128;
#pragma unroll
  for (int fm = 0; fm < 4; ++fm) {
#pragma unroll
    for (int j = 0; j < 4; ++j) {
      const int rowt = wm * 64 + fm * 16 + lg * 4 + j;
      const int r = r0 + rowt;
      if constexpr (MODE == 0 || MODE == 1) {
        if (r >= cnt) continue;
      }
      int slot = 0;
      float rsc = 0.f;
      if constexpr (MODE == 1) { slot = lists[e * T_ + r]; rsc = pw[slot]; }
      if constexpr (MODE == 3) rsc = gate[r];
#pragma unroll
      for (int fn = 0; fn < 4; ++fn) {
        const int c = nt * 128 + wn * 64 + fn * 16 + lr;
        float v = acc0[fm][fn][j];
        if constexpr (MODE == 0) {
          float g = v, u = acc1[fm][fn][j];
          float h = g / (1.f + expf(-g)) * u;
          outb[(size_t)(roff + r) * F_ + c] = f2b(h);
        } else if constexpr (MODE == 1) {
          outb[(size_t)slot * D_ + c] = f2b(rsc * v);
        } else if constexpr (MODE == 2) {
          float g = v, u = acc1[fm][fn][j];
          float h = g / (1.f + expf(-g)) * u;
          outb[(size_t)r * FS_ + c] = f2b(h);
        } else {
          float o = v * rsc + b2f(pairb[(size_t)(2 * r) * D_ + c]) + b2f(pairb[(size_t)(2 * r + 1) * D_ + c]);
          outf[(size_t)r * D_ + c] = o;
        }
      }
    }
  }
}

// ---------------- launch ----------------
extern "C" void kernel_launch(void* const* d_in, const int* in_sizes, int n_in,
                              void* d_out, int out_size, void* d_ws, size_t ws_size,
                              hipStream_t stream) {
  const float* x   = (const float*)d_in[0];
  const float* rw  = (const float*)d_in[1];
  const float* Wg  = (const float*)d_in[2];
  const float* Wu  = (const float*)d_in[3];
  const float* Wd  = (const float*)d_in[4];
  const float* Sg  = (const float*)d_in[5];
  const float* Su  = (const float*)d_in[6];
  const float* Sd  = (const float*)d_in[7];
  const float* sgw = (const float*)d_in[8];
  float* out = (float*)d_out;

  unsigned char* ws = (unsigned char*)d_ws;
  u16* xb    = (u16*)(ws + OFF_XB);
  u16* wgT   = (u16*)(ws + OFF_WGT);
  u16* wuT   = (u16*)(ws + OFF_WUT);
  u16* wdT   = (u16*)(ws + OFF_WDT);
  u16* sgT   = (u16*)(ws + OFF_SGT);
  u16* suT   = (u16*)(ws + OFF_SUT);
  u16* sdT   = (u16*)(ws + OFF_SDT);
  u16* hb    = (u16*)(ws + OFF_HB);
  u16* hs    = (u16*)(ws + OFF_HS);
  u16* pairb = (u16*)(ws + OFF_PAIR);
  float* pwf   = (float*)(ws + OFF_PW);
  float* gatef = (float*)(ws + OFF_GATE);
  int* cnti    = (int*)(ws + OFF_CNT);
  int* roffi   = (int*)(ws + OFF_ROFF);
  int* top2i   = (int*)(ws + OFF_TOP2);
  int* listsi  = (int*)(ws + OFF_LIST);

  transpose_cvt_kernel<<<dim3(F_ / 32, D_ / 32, E_), dim3(32, 8), 0, stream>>>(Wg, wgT, D_, F_);
  transpose_cvt_kernel<<<dim3(F_ / 32, D_ / 32, E_), dim3(32, 8), 0, stream>>>(Wu, wuT, D_, F_);
  transpose_cvt_kernel<<<dim3(D_ / 32, F_ / 32, E_), dim3(32, 8), 0, stream>>>(Wd, wdT, F_, D_);
  transpose_cvt_kernel<<<dim3(FS_ / 32, D_ / 32, 1), dim3(32, 8), 0, stream>>>(Sg, sgT, D_, FS_);
  transpose_cvt_kernel<<<dim3(FS_ / 32, D_ / 32, 1), dim3(32, 8), 0, stream>>>(Su, suT, D_, FS_);
  transpose_cvt_kernel<<<dim3(D_ / 32, FS_ / 32, 1), dim3(32, 8), 0, stream>>>(Sd, sdT, FS_, D_);

  router_kernel<<<1024, 256, 0, stream>>>((const float4*)x, (const float4*)rw,
                                          (const float4*)sgw, top2i, pwf, gatef,
                                          (ushort4*)xb);
  compact_kernel<<<E_, 256, 0, stream>>>(top2i, listsi, cnti);
  scan_kernel<<<1, 64, 0, stream>>>(cnti, roffi);

  // expert gate+up: K=1024, N=512
  moe_gemm<0><<<dim3(64, 4, 16), 256, 49152, stream>>>(xb, wgT, wuT, hb, nullptr,
                                                       cnti, roffi, listsi, pwf, gatef, nullptr, 1024);
  // expert down: K=512, N=1024
  moe_gemm<1><<<dim3(64, 8, 16), 256, 32768, stream>>>(hb, wdT, nullptr, pairb, nullptr,
                                                       cnti, roffi, listsi, pwf, gatef, nullptr, 512);
  // shared gate+up: K=1024, N=2048
  moe_gemm<2><<<dim3(64, 16, 1), 256, 49152, stream>>>(xb, sgT, suT, hs, nullptr,
                                                       cnti, roffi, listsi, pwf, gatef, nullptr, 1024);
  // shared down + final combine: K=2048, N=1024
  moe_gemm<3><<<dim3(64, 8, 1), 256, 32768, stream>>>(hs, sdT, nullptr, nullptr, out,
                                                      cnti, roffi, listsi, pwf, gatef, pairb, 2048);

  (void)in_sizes; (void)n_in; (void)out_size; (void)ws_size;
}